// Round 3
// baseline (711.932 us; speedup 1.0000x reference)
//
#include <hip/hip_runtime.h>
#include <math.h>

// ---------------- FDTD time-skewed tiling, register-resident fields ----------------
// 400x400 grid, 300 steps, batch 2.
// Retiled for occupancy: interior 16 rows x 40 cols, ext 40 rows x 64 cols.
// Block = 512 threads = 8 waves; wave w owns ext rows [5w, 5w+5), lane = ext col.
// Grid = 25 x 10 x 2 = 500 blocks -> ~2 blocks/CU -> 4 waves/SIMD (latency hiding).
// Column neighbors via __shfl; wave-boundary rows via ping-pong LDS exchange;
// ONE barrier per step. 25 rounds x 12 steps = 300. Cone: 40-2*12=16, 64-2*12=40.
#define NXg 400
#define NYg 400
#define NN (NXg * NYg)
#define SRC_I 30
#define DET_I 370
#define TROW 16         // interior rows per tile
#define TCOL 40         // interior cols per tile
#define HALO 12
#define RREG 5          // rows per wave (8 waves * 5 = 40 ext rows)
#define NTR 25          // row tiles (25*16 = 400)
#define NTC 10          // col tiles (10*40 = 400)
#define ROUNDS 25
#define RSTEPS 12
#define NB 2
#define XSLOT 576       // 9 slots * 64 lanes (ghost slots = zeros)

static constexpr float DT_F     = (float)(0.5 * 25e-9 / 299792458.0);     // COURANT*DX/C0
static constexpr float PERIOD_F = (float)(1550e-9 / 299792458.0);         // WAVELENGTH/C0
static constexpr float TWOPI_F  = (float)(2.0 * 3.14159265358979323846);
static constexpr float PI_F     = (float)3.14159265358979323846;

// shared helper so the redundant "row above" Hy update compiles identically
__device__ __forceinline__ float hupd(float damp, float h, float d) {
    return damp * (h + 0.5f * d);
}

// ---- one-time (per call) setup: zero states, build rc = COURANT/eps, damp profile ----
__global__ void fdtd_setup(const float* __restrict__ radius,
                           float* __restrict__ Ez_g, float* __restrict__ Hx_g,
                           float* __restrict__ Hy_g, float* __restrict__ rc_g,
                           float* __restrict__ px_g)
{
    __shared__ float rsh[64];
    if (threadIdx.x < 64) {
        float r = radius[threadIdx.x];
        rsh[threadIdx.x] = (r < 0.3f) ? 0.f : r;
    }
    __syncthreads();

    int idx = blockIdx.x * blockDim.x + threadIdx.x;
    if (idx >= NN) return;
    int i = idx / NYg, j = idx % NYg;

    Ez_g[idx] = 0.f; Ez_g[idx + NN] = 0.f;
    Hx_g[idx] = 0.f; Hx_g[idx + NN] = 0.f;
    Hy_g[idx] = 0.f; Hy_g[idx + NN] = 0.f;

    float eps = 1.0f;
    int dj = j - 70;  // port columns: [70..89],[150..169],[230..249],[310..329]
    bool port = (dj >= 0) && (dj < 260) && ((dj % 80) < 20);
    if (port && (i < SRC_I || i >= DET_I)) eps = 2.8f;
    if (i >= 80 && i < 320 && j >= 80 && j < 320) {
        // design region: 8x8 circles, spacing 30, centers 15+30k; r<0.3 -> 0
        float x = (float)(i - 80), y = (float)(j - 80);
        bool inside = false;
        #pragma unroll 8
        for (int a = 0; a < 64; ++a) {
            float r = rsh[a];
            float cx = (float)(15 + 30 * (a >> 3));
            float cy = (float)(15 + 30 * (a & 7));
            float dx = x - cx, dy = y - cy;
            if (dx * dx + dy * dy <= r * r) inside = true;
        }
        eps = inside ? 1.0f : 2.8f;
    }
    rc_g[idx] = 0.5f / eps;

    if (idx < NXg) {
        // damp profile in double, then cast: matches numpy f64 exp -> f32
        double prof = 1.0;
        if (idx < 10) {
            double rmp = (10.0 - (double)idx - 0.5) / 10.0;
            prof = exp(-0.5 * rmp * rmp * rmp);
        } else if (idx >= NXg - 10) {
            double rmp = ((double)(idx - (NXg - 10)) + 0.5) / 10.0;
            prof = exp(-0.5 * rmp * rmp * rmp);
        }
        px_g[idx] = (float)prof;
    }
}

// ---- one round: load regs -> 12 local steps (regs + shuffles) -> store interior ----
__global__ __launch_bounds__(512, 4)
void fdtd_round(const float* __restrict__ phase,
                float* __restrict__ Ez_g, float* __restrict__ Hx_g,
                float* __restrict__ Hy_g, const float* __restrict__ rc_g,
                const float* __restrict__ px_g, int t0)
{
    // ping-pong wave-boundary exchange buffers
    __shared__ float xEz0[2][XSLOT];   // slot w   = wave w's Ez row0; slot 8 ghost
    __shared__ float xEzL[2][XSLOT];   // slot w+1 = wave w's Ez last row; slot 0 ghost
    __shared__ float xHyL[2][XSLOT];   // slot w+1 = wave w's Hy last row (pre-update)

    const int tid = threadIdx.x;
    const int w   = tid >> 6;
    const int lj  = tid & 63;
    const int b   = blockIdx.z;
    const int gx0 = blockIdx.y * TROW - HALO;   // ext row 0 (global)
    const int gy0 = blockIdx.x * TCOL - HALO;   // ext col 0 (global)
    const int gj  = gy0 + lj;
    const int gib = gx0 + RREG * w;             // global row of register r=0
    const size_t bb = (size_t)b * NN;

    if (tid < 64) {
        #pragma unroll
        for (int p = 0; p < 2; ++p) {
            xEz0[p][512 + tid] = 0.f;
            xEzL[p][tid] = 0.f;
            xHyL[p][tid] = 0.f;
        }
    }

    const bool jin = (gj >= 0) && (gj < NYg);
    const float pyv = jin ? px_g[gj] : 0.f;

    float Ez[RREG], Hx[RREG], Hy[RREG], rc[RREG], dmp[RREG];
    #pragma unroll
    for (int r = 0; r < RREG; ++r) {
        const int gi = gib + r;
        const bool in = jin && (gi >= 0) && (gi < NXg);
        if (in) {
            const size_t go = bb + (size_t)gi * NYg + gj;
            Ez[r] = Ez_g[go]; Hx[r] = Hx_g[go]; Hy[r] = Hy_g[go];
            rc[r] = rc_g[(size_t)gi * NYg + gj];
            dmp[r] = px_g[gi] * pyv;
        } else {
            Ez[r] = 0.f; Hx[r] = 0.f; Hy[r] = 0.f; rc[r] = 0.5f; dmp[r] = 0.f;
        }
    }
    float dmpA = 0.f;   // damp of the row just above this wave's rows
    { const int giA = gib - 1; if (jin && giA >= 0 && giA < NXg) dmpA = px_g[giA] * pyv; }

    const int djp = gj - 70;
    const int pport = (djp >= 0 && djp < 260 && (djp % 80) < 20) ? (djp / 80) : -1;
    const float phv = (pport >= 0) ? phase[b * 4 + pport] : 0.f;
    const bool gYlt = (gj < NYg - 1);
    const bool gYgt = (gj > 0);
    const bool hasSrc = (gib <= SRC_I) && (SRC_I < gib + RREG);

    for (int s = 0; s < RSTEPS; ++s) {
        const int p = s & 1;
        // publish wave-boundary rows (pre-update values)
        xEz0[p][(w << 6) + lj] = Ez[0];
        xEzL[p][((w + 1) << 6) + lj] = Ez[RREG - 1];
        xHyL[p][((w + 1) << 6) + lj] = Hy[RREG - 1];
        __syncthreads();
        const float ezB  = xEz0[p][((w + 1) << 6) + lj];   // Ez of row below (wave w+1 row0)
        const float ezAL = xEzL[p][(w << 6) + lj];         // Ez of row above (wave w-1 last)
        const float hyAL = xHyL[p][(w << 6) + lj];         // Hy of row above (pre-update)
        // redundant Hy update of the row above — bitwise-identical inputs/expression
        const float dexA = (gib - 1 < NXg - 1) ? (Ez[0] - ezAL) : 0.f;
        const float hyA  = hupd(dmpA, hyAL, dexA);

        // ---- H update (registers + shuffles) ----
        float ezn[RREG];
        #pragma unroll
        for (int r = 0; r < RREG - 1; ++r) ezn[r] = Ez[r + 1];
        ezn[RREG - 1] = ezB;
        #pragma unroll
        for (int r = 0; r < RREG; ++r) {
            const int gi = gib + r;
            const float ezr = __shfl_down(Ez[r], 1, 64);
            const float dey = gYlt ? (ezr - Ez[r]) : 0.f;
            const float dex = (gi < NXg - 1) ? (ezn[r] - Ez[r]) : 0.f;
            Hx[r] = hupd(dmp[r], Hx[r], -dey);
            Hy[r] = hupd(dmp[r], Hy[r], dex);
        }

        // ---- E update + soft source ----
        const float tf = (float)(t0 + s);
        float hyprev = hyA;
        #pragma unroll
        for (int r = 0; r < RREG; ++r) {
            const int gi = gib + r;
            const float hxl = __shfl_up(Hx[r], 1, 64);
            const float dhyx = (gi > 0) ? (Hy[r] - hyprev) : 0.f;
            const float dhxy = gYgt ? (Hx[r] - hxl) : 0.f;
            float ez = dmp[r] * (Ez[r] + rc[r] * (dhyx - dhxy));
            if (hasSrc && (gi == SRC_I) && (pport >= 0)) {
                const float a = tf * DT_F;                  // JAX f32 op order
                ez += sinf(TWOPI_F * a / PERIOD_F + PI_F * phv);
            }
            Ez[r] = ez;
            hyprev = Hy[r];
        }
        // single barrier per step: ping-pong buffers make a 2nd barrier unnecessary
    }

    // store interior rows [HALO, HALO+TROW), cols [HALO, HALO+TCOL) — exact tiling
    if (lj >= HALO && lj < HALO + TCOL) {
        #pragma unroll
        for (int r = 0; r < RREG; ++r) {
            const int li = w * RREG + r;
            if (li >= HALO && li < HALO + TROW) {
                const int gi = gx0 + li;
                const size_t go = bb + (size_t)gi * NYg + gj;
                Ez_g[go] = Ez[r];
                Hx_g[go] = Hx[r];
                Hy_g[go] = Hy[r];
            }
        }
    }
}

// ---- detector gather: out[b][p][k] = Ez[DET_I, 80*(p+1)-10+k] ----
__global__ void fdtd_gather(const float* __restrict__ Ez_g, float* __restrict__ out)
{
    int idx = threadIdx.x;
    if (idx < NB * 80) {
        int b = idx / 80, rem = idx % 80, p = rem / 20, k = rem % 20;
        int gj = (p + 1) * 80 - 10 + k;
        out[idx] = Ez_g[(size_t)b * NN + (size_t)DET_I * NYg + gj];
    }
}

extern "C" void kernel_launch(void* const* d_in, const int* in_sizes, int n_in,
                              void* d_out, int out_size, void* d_ws, size_t ws_size,
                              hipStream_t stream)
{
    const float* phase  = (const float*)d_in[0];   // (2,4) f32
    const float* radius = (const float*)d_in[1];   // (8,8) f32
    float* ws = (float*)d_ws;
    // workspace layout (floats): Ez[2*NN] | Hx[2*NN] | Hy[2*NN] | rc[NN] | px[400]
    float* Ez_g = ws;
    float* Hx_g = ws + 2 * NN;
    float* Hy_g = ws + 4 * NN;
    float* rc_g = ws + 6 * NN;
    float* px_g = ws + 7 * NN;

    fdtd_setup<<<(NN + 255) / 256, 256, 0, stream>>>(radius, Ez_g, Hx_g, Hy_g, rc_g, px_g);

    dim3 grid(NTC, NTR, NB);
    for (int r = 0; r < ROUNDS; ++r) {
        fdtd_round<<<grid, 512, 0, stream>>>(phase, Ez_g, Hx_g, Hy_g, rc_g, px_g, r * RSTEPS);
    }

    fdtd_gather<<<1, 256, 0, stream>>>(Ez_g, (float*)d_out);
}

// Round 4
// 587.410 us; speedup vs baseline: 1.2120x; 1.2120x over previous
//
#include <hip/hip_runtime.h>
#include <math.h>

// ---------------- FDTD time-skewed tiling, register-resident, 2 cols/lane ----------------
// 400x400 grid, 300 steps, batch 2.
// Ext tile: 128 cols x 40 rows; interior 104 cols x 16 rows (cone: 128-24, 40-24).
// Block = 512 threads = 8 waves; wave w owns ext rows [5w,5w+5); lane lj owns ext
// cols {2lj, 2lj+1} (global pair even-aligned -> ports/edges never straddle a pair).
// Intra-pair col neighbor = register; pair boundary = 1 shfl; row wave-boundary =
// ping-pong LDS float2 exchange; ONE barrier per step. DS insts/lane-step: 22 -> 16.
// Grid 4 x 25 x 2 = 200 blocks (1 block/CU). 25 rounds x 12 steps = 300.
#define NXg 400
#define NYg 400
#define NN (NXg * NYg)
#define SRC_I 30
#define DET_I 370
#define TROW 16         // interior rows per tile (25*16 = 400)
#define TCOL 104        // interior cols per tile (4 tiles, last clipped at 400)
#define HALO 12
#define RREG 5          // rows per wave (8 waves * 5 = 40 ext rows)
#define NTR 25
#define NTC 4
#define ROUNDS 25
#define RSTEPS 12
#define NB 2

static constexpr float DT_F     = (float)(0.5 * 25e-9 / 299792458.0);     // COURANT*DX/C0
static constexpr float PERIOD_F = (float)(1550e-9 / 299792458.0);         // WAVELENGTH/C0
static constexpr float TWOPI_F  = (float)(2.0 * 3.14159265358979323846);
static constexpr float PI_F     = (float)3.14159265358979323846;

// shared helper so the redundant "row above" Hy update compiles identically
__device__ __forceinline__ float hupd(float damp, float h, float d) {
    return damp * (h + 0.5f * d);
}

// ---- one-time (per call) setup: zero states, build rc = COURANT/eps, damp profile ----
__global__ void fdtd_setup(const float* __restrict__ radius,
                           float* __restrict__ Ez_g, float* __restrict__ Hx_g,
                           float* __restrict__ Hy_g, float* __restrict__ rc_g,
                           float* __restrict__ px_g)
{
    __shared__ float rsh[64];
    if (threadIdx.x < 64) {
        float r = radius[threadIdx.x];
        rsh[threadIdx.x] = (r < 0.3f) ? 0.f : r;
    }
    __syncthreads();

    int idx = blockIdx.x * blockDim.x + threadIdx.x;
    if (idx >= NN) return;
    int i = idx / NYg, j = idx % NYg;

    Ez_g[idx] = 0.f; Ez_g[idx + NN] = 0.f;
    Hx_g[idx] = 0.f; Hx_g[idx + NN] = 0.f;
    Hy_g[idx] = 0.f; Hy_g[idx + NN] = 0.f;

    float eps = 1.0f;
    int dj = j - 70;  // port columns: [70..89],[150..169],[230..249],[310..329]
    bool port = (dj >= 0) && (dj < 260) && ((dj % 80) < 20);
    if (port && (i < SRC_I || i >= DET_I)) eps = 2.8f;
    if (i >= 80 && i < 320 && j >= 80 && j < 320) {
        // design region: 8x8 circles, spacing 30, centers 15+30k; r<0.3 -> 0
        float x = (float)(i - 80), y = (float)(j - 80);
        bool inside = false;
        #pragma unroll 8
        for (int a = 0; a < 64; ++a) {
            float r = rsh[a];
            float cx = (float)(15 + 30 * (a >> 3));
            float cy = (float)(15 + 30 * (a & 7));
            float dx = x - cx, dy = y - cy;
            if (dx * dx + dy * dy <= r * r) inside = true;
        }
        eps = inside ? 1.0f : 2.8f;
    }
    rc_g[idx] = 0.5f / eps;

    if (idx < NXg) {
        // damp profile in double, then cast: matches numpy f64 exp -> f32
        double prof = 1.0;
        if (idx < 10) {
            double rmp = (10.0 - (double)idx - 0.5) / 10.0;
            prof = exp(-0.5 * rmp * rmp * rmp);
        } else if (idx >= NXg - 10) {
            double rmp = ((double)(idx - (NXg - 10)) + 0.5) / 10.0;
            prof = exp(-0.5 * rmp * rmp * rmp);
        }
        px_g[idx] = (float)prof;
    }
}

// ---- one round: load regs -> 12 local steps (regs + shuffles) -> store interior ----
__global__ __launch_bounds__(512)
void fdtd_round(const float* __restrict__ phase,
                float* __restrict__ Ez_g, float* __restrict__ Hx_g,
                float* __restrict__ Hy_g, const float* __restrict__ rc_g,
                const float* __restrict__ px_g, int t0)
{
    // ping-pong wave-boundary exchange buffers (float2 = both cols of a lane)
    __shared__ float2 xEz0[2][576];   // slot w   = wave w's Ez row0;    slot 8 ghost
    __shared__ float2 xEzL[2][576];   // slot w+1 = wave w's Ez row4;    slot 0 ghost
    __shared__ float2 xHyL[2][576];   // slot w+1 = wave w's Hy row4 (pre-update)

    const int tid = threadIdx.x;
    const int w   = tid >> 6;
    const int lj  = tid & 63;
    const int b   = blockIdx.z;
    const int gx0 = blockIdx.y * TROW - HALO;       // ext row 0 (global)
    const int gy0 = blockIdx.x * TCOL - HALO;       // ext col 0 (global), even
    const int gj0 = gy0 + 2 * lj;                   // even; gj1 = gj0+1
    const int gj1 = gj0 + 1;
    const int gib = gx0 + RREG * w;                 // global row of register r=0
    const size_t bb = (size_t)b * NN;

    if (tid < 64) {
        #pragma unroll
        for (int p = 0; p < 2; ++p) {
            xEz0[p][512 + tid] = make_float2(0.f, 0.f);
            xEzL[p][tid]       = make_float2(0.f, 0.f);
            xHyL[p][tid]       = make_float2(0.f, 0.f);
        }
    }

    // col pair is fully in-grid iff 0 <= gj0 <= 398 (pairs never straddle the edge)
    const bool jin  = (gj0 >= 0) && (gj0 < NYg);
    const float pyv0 = jin ? px_g[gj0] : 0.f;
    const float pyv1 = jin ? px_g[gj1] : 0.f;

    float Ez0[RREG], Ez1[RREG], Hx0[RREG], Hx1[RREG], Hy0[RREG], Hy1[RREG];
    float rc0[RREG], rc1[RREG], dm0[RREG], dm1[RREG];
    #pragma unroll
    for (int r = 0; r < RREG; ++r) {
        const int gi = gib + r;
        const bool in = jin && (gi >= 0) && (gi < NXg);
        if (in) {
            const size_t f2 = (bb + (size_t)gi * NYg + gj0) >> 1;
            const float2 e = ((const float2*)Ez_g)[f2];
            const float2 hx = ((const float2*)Hx_g)[f2];
            const float2 hy = ((const float2*)Hy_g)[f2];
            const float2 rc = ((const float2*)rc_g)[((size_t)gi * NYg + gj0) >> 1];
            const float pxr = px_g[gi];
            Ez0[r] = e.x;  Ez1[r] = e.y;
            Hx0[r] = hx.x; Hx1[r] = hx.y;
            Hy0[r] = hy.x; Hy1[r] = hy.y;
            rc0[r] = rc.x; rc1[r] = rc.y;
            dm0[r] = pxr * pyv0; dm1[r] = pxr * pyv1;
        } else {
            Ez0[r] = 0.f; Ez1[r] = 0.f; Hx0[r] = 0.f; Hx1[r] = 0.f;
            Hy0[r] = 0.f; Hy1[r] = 0.f; rc0[r] = 0.5f; rc1[r] = 0.5f;
            dm0[r] = 0.f; dm1[r] = 0.f;
        }
    }
    float dmA0 = 0.f, dmA1 = 0.f;   // damp of the row just above this wave's rows
    { const int giA = gib - 1;
      if (giA >= 0 && giA < NXg) { const float pxA = px_g[giA]; dmA0 = pxA * pyv0; dmA1 = pxA * pyv1; } }

    // port id is pair-uniform (port windows are even-aligned, width 20)
    const int djp = gj0 - 70;
    const int pport = (djp >= 0 && djp < 260 && (djp % 80) < 20) ? (djp / 80) : -1;
    const float phv = (pport >= 0) ? phase[b * 4 + pport] : 0.f;
    const bool e1ok = (gj1 < NYg - 1);   // dey zero-pad at global col 399 (odd -> col1)
    const bool l0ok = (gj0 > 0);         // dhxy zero-pad at global col 0 (even -> col0)
    const bool hasSrc = (gib <= SRC_I) && (SRC_I < gib + RREG);

    for (int s = 0; s < RSTEPS; ++s) {
        const int p = s & 1;
        // publish wave-boundary rows (pre-update values)
        xEz0[p][(w << 6) + lj]       = make_float2(Ez0[0], Ez1[0]);
        xEzL[p][((w + 1) << 6) + lj] = make_float2(Ez0[RREG - 1], Ez1[RREG - 1]);
        xHyL[p][((w + 1) << 6) + lj] = make_float2(Hy0[RREG - 1], Hy1[RREG - 1]);
        __syncthreads();
        const float2 ezB  = xEz0[p][((w + 1) << 6) + lj];  // Ez of row below (wave w+1 row0)
        const float2 ezAL = xEzL[p][(w << 6) + lj];        // Ez of row above (wave w-1 last)
        const float2 hyAL = xHyL[p][(w << 6) + lj];        // Hy of row above (pre-update)
        // redundant Hy update of the row above — bitwise-identical inputs/expression
        const bool rAok = (gib - 1 < NXg - 1);
        const float dexA0 = rAok ? (Ez0[0] - ezAL.x) : 0.f;
        const float dexA1 = rAok ? (Ez1[0] - ezAL.y) : 0.f;
        float hyp0 = hupd(dmA0, hyAL.x, dexA0);
        float hyp1 = hupd(dmA1, hyAL.y, dexA1);

        // ---- H update (registers + 1 shfl per row) ----
        #pragma unroll
        for (int r = 0; r < RREG; ++r) {
            const int gi = gib + r;
            const float eznx0 = (r < RREG - 1) ? Ez0[r + 1] : ezB.x;
            const float eznx1 = (r < RREG - 1) ? Ez1[r + 1] : ezB.y;
            const float ezr   = __shfl_down(Ez0[r], 1, 64);       // col 2lj+2
            const float dey0 = Ez1[r] - Ez0[r];                   // in-pair, never at edge
            const float dey1 = e1ok ? (ezr - Ez1[r]) : 0.f;
            const float dex0 = (gi < NXg - 1) ? (eznx0 - Ez0[r]) : 0.f;
            const float dex1 = (gi < NXg - 1) ? (eznx1 - Ez1[r]) : 0.f;
            Hx0[r] = hupd(dm0[r], Hx0[r], -dey0);
            Hx1[r] = hupd(dm1[r], Hx1[r], -dey1);
            Hy0[r] = hupd(dm0[r], Hy0[r], dex0);
            Hy1[r] = hupd(dm1[r], Hy1[r], dex1);
        }

        // ---- E update + soft source (1 shfl per row) ----
        const float tf = (float)(t0 + s);
        #pragma unroll
        for (int r = 0; r < RREG; ++r) {
            const int gi = gib + r;
            const float hxl = __shfl_up(Hx1[r], 1, 64);           // col 2lj-1
            const float dhyx0 = (gi > 0) ? (Hy0[r] - hyp0) : 0.f;
            const float dhyx1 = (gi > 0) ? (Hy1[r] - hyp1) : 0.f;
            const float dhxy0 = l0ok ? (Hx0[r] - hxl) : 0.f;
            const float dhxy1 = Hx1[r] - Hx0[r];                  // in-pair, never at edge
            float ez0 = dm0[r] * (Ez0[r] + rc0[r] * (dhyx0 - dhxy0));
            float ez1 = dm1[r] * (Ez1[r] + rc1[r] * (dhyx1 - dhxy1));
            if (hasSrc && (gi == SRC_I) && (pport >= 0)) {
                const float a = tf * DT_F;                        // JAX f32 op order
                const float sv = sinf(TWOPI_F * a / PERIOD_F + PI_F * phv);
                ez0 += sv; ez1 += sv;
            }
            Ez0[r] = ez0; Ez1[r] = ez1;
            hyp0 = Hy0[r]; hyp1 = Hy1[r];
        }
        // single barrier per step: ping-pong buffers make a 2nd barrier unnecessary
    }

    // store interior: ext-local cols [12,116) -> lj in [6,57]; rows [12,28); clip at col 400
    if (lj >= 6 && lj <= 57 && gj0 < NYg) {
        #pragma unroll
        for (int r = 0; r < RREG; ++r) {
            const int li = w * RREG + r;
            if (li >= HALO && li < HALO + TROW) {
                const int gi = gx0 + li;
                const size_t f2 = (bb + (size_t)gi * NYg + gj0) >> 1;
                ((float2*)Ez_g)[f2] = make_float2(Ez0[r], Ez1[r]);
                ((float2*)Hx_g)[f2] = make_float2(Hx0[r], Hx1[r]);
                ((float2*)Hy_g)[f2] = make_float2(Hy0[r], Hy1[r]);
            }
        }
    }
}

// ---- detector gather: out[b][p][k] = Ez[DET_I, 80*(p+1)-10+k] ----
__global__ void fdtd_gather(const float* __restrict__ Ez_g, float* __restrict__ out)
{
    int idx = threadIdx.x;
    if (idx < NB * 80) {
        int b = idx / 80, rem = idx % 80, p = rem / 20, k = rem % 20;
        int gj = (p + 1) * 80 - 10 + k;
        out[idx] = Ez_g[(size_t)b * NN + (size_t)DET_I * NYg + gj];
    }
}

extern "C" void kernel_launch(void* const* d_in, const int* in_sizes, int n_in,
                              void* d_out, int out_size, void* d_ws, size_t ws_size,
                              hipStream_t stream)
{
    const float* phase  = (const float*)d_in[0];   // (2,4) f32
    const float* radius = (const float*)d_in[1];   // (8,8) f32
    float* ws = (float*)d_ws;
    // workspace layout (floats): Ez[2*NN] | Hx[2*NN] | Hy[2*NN] | rc[NN] | px[400]
    float* Ez_g = ws;
    float* Hx_g = ws + 2 * NN;
    float* Hy_g = ws + 4 * NN;
    float* rc_g = ws + 6 * NN;
    float* px_g = ws + 7 * NN;

    fdtd_setup<<<(NN + 255) / 256, 256, 0, stream>>>(radius, Ez_g, Hx_g, Hy_g, rc_g, px_g);

    dim3 grid(NTC, NTR, NB);
    for (int r = 0; r < ROUNDS; ++r) {
        fdtd_round<<<grid, 512, 0, stream>>>(phase, Ez_g, Hx_g, Hy_g, rc_g, px_g, r * RSTEPS);
    }

    fdtd_gather<<<1, 256, 0, stream>>>(Ez_g, (float*)d_out);
}

// Round 5
// 549.849 us; speedup vs baseline: 1.2948x; 1.0683x over previous
//
#include <hip/hip_runtime.h>
#include <math.h>

// ---------------- FDTD time-skewed tiling, register fields, barrier-free ----------------
// 400x400 grid, 300 steps, batch 2. Tile: 40x40 interior + halo 12 -> 64x64 ext.
// Block = 512 threads = 8 waves; wave w owns ext rows [8w, 8w+8), lane = ext col.
// Fields in registers (8 rows/lane). Column neighbors via __shfl. Wave-boundary rows
// via ping-pong LDS slots guarded by PER-WAVE monotone step flags (acquire/release,
// workgroup scope) -- NO per-step __syncthreads. Waves free-run with <=1 step skew;
// mutual dependency gives automatic backpressure (slot for step s+2 is only written
// after both neighbors consumed step s). One barrier per ROUND (ghost/flag init).
// 25 rounds x 12 steps = 300. Cone: 64-2*12=40 exact.
#define NXg 400
#define NYg 400
#define NN (NXg * NYg)
#define SRC_I 30
#define DET_I 370
#define TILE_B 40
#define HALO 12
#define NTI 10          // tiles per dim (10*40 = 400 exact)
#define ROUNDS 25
#define RSTEPS 12
#define NB 2
#define XSLOT 576       // 9 slots * 64 lanes (ghost slots = zeros)

static constexpr float DT_F     = (float)(0.5 * 25e-9 / 299792458.0);     // COURANT*DX/C0
static constexpr float PERIOD_F = (float)(1550e-9 / 299792458.0);         // WAVELENGTH/C0
static constexpr float TWOPI_F  = (float)(2.0 * 3.14159265358979323846);
static constexpr float PI_F     = (float)3.14159265358979323846;

// shared helper so the redundant "row above" Hy update compiles identically
__device__ __forceinline__ float hupd(float damp, float h, float d) {
    return damp * (h + 0.5f * d);
}

// ---- one-time (per call) setup: zero states, build rc = COURANT/eps, damp profile ----
__global__ void fdtd_setup(const float* __restrict__ radius,
                           float* __restrict__ Ez_g, float* __restrict__ Hx_g,
                           float* __restrict__ Hy_g, float* __restrict__ rc_g,
                           float* __restrict__ px_g)
{
    __shared__ float rsh[64];
    if (threadIdx.x < 64) {
        float r = radius[threadIdx.x];
        rsh[threadIdx.x] = (r < 0.3f) ? 0.f : r;
    }
    __syncthreads();

    int idx = blockIdx.x * blockDim.x + threadIdx.x;
    if (idx >= NN) return;
    int i = idx / NYg, j = idx % NYg;

    Ez_g[idx] = 0.f; Ez_g[idx + NN] = 0.f;
    Hx_g[idx] = 0.f; Hx_g[idx + NN] = 0.f;
    Hy_g[idx] = 0.f; Hy_g[idx + NN] = 0.f;

    float eps = 1.0f;
    int dj = j - 70;  // port columns: [70..89],[150..169],[230..249],[310..329]
    bool port = (dj >= 0) && (dj < 260) && ((dj % 80) < 20);
    if (port && (i < SRC_I || i >= DET_I)) eps = 2.8f;
    if (i >= 80 && i < 320 && j >= 80 && j < 320) {
        // design region: 8x8 circles, spacing 30, centers 15+30k; r<0.3 -> 0
        float x = (float)(i - 80), y = (float)(j - 80);
        bool inside = false;
        #pragma unroll 8
        for (int a = 0; a < 64; ++a) {
            float r = rsh[a];
            float cx = (float)(15 + 30 * (a >> 3));
            float cy = (float)(15 + 30 * (a & 7));
            float dx = x - cx, dy = y - cy;
            if (dx * dx + dy * dy <= r * r) inside = true;
        }
        eps = inside ? 1.0f : 2.8f;
    }
    rc_g[idx] = 0.5f / eps;

    if (idx < NXg) {
        // damp profile in double, then cast: matches numpy f64 exp -> f32
        double prof = 1.0;
        if (idx < 10) {
            double rmp = (10.0 - (double)idx - 0.5) / 10.0;
            prof = exp(-0.5 * rmp * rmp * rmp);
        } else if (idx >= NXg - 10) {
            double rmp = ((double)(idx - (NXg - 10)) + 0.5) / 10.0;
            prof = exp(-0.5 * rmp * rmp * rmp);
        }
        px_g[idx] = (float)prof;
    }
}

// ---- one round: load regs -> 12 local steps (flag-synced, no barrier) -> store ----
__global__ __launch_bounds__(512)
void fdtd_round(const float* __restrict__ phase,
                float* __restrict__ Ez_g, float* __restrict__ Hx_g,
                float* __restrict__ Hy_g, const float* __restrict__ rc_g,
                const float* __restrict__ px_g, int t0)
{
    // ping-pong wave-boundary exchange buffers
    __shared__ float xEz0[2][XSLOT];   // slot w   = wave w's Ez row0; slot 8 ghost; read by w-1... (consumer w reads slot w+1)
    __shared__ float xEzL[2][XSLOT];   // slot w+1 = wave w's Ez row7; slot 0 ghost; consumer w reads slot w
    __shared__ float xHyL[2][XSLOT];   // slot w+1 = wave w's Hy row7 (pre-update)
    // monotone per-producer step flags: value s => slot[s&1] holds data for step s
    __shared__ int fEz0[9];            // producer w -> fEz0[w];   ghost index 8
    __shared__ int fEzL[9];            // producer w -> fEzL[w+1]; ghost index 0

    const int tid = threadIdx.x;
    const int w   = tid >> 6;
    const int lj  = tid & 63;
    const int b   = blockIdx.z;
    const int gx0 = blockIdx.x * TILE_B - HALO;
    const int gy0 = blockIdx.y * TILE_B - HALO;
    const int gj  = gy0 + lj;
    const int gib = gx0 + 8 * w;       // global row of register r=0
    const size_t bb = (size_t)b * NN;

    // ---- init ghosts + flags (wave 0), then ONE barrier ----
    if (tid < 64) {
        #pragma unroll
        for (int p = 0; p < 2; ++p) {
            xEz0[p][512 + tid] = 0.f;   // ghost slot 8 (below wave 7)
            xEzL[p][tid] = 0.f;         // ghost slot 0 (above wave 0)
            xHyL[p][tid] = 0.f;
        }
        if (tid < 9) { fEz0[tid] = -1; fEzL[tid] = -1; }
        if (tid == 0) { fEz0[8] = 0x7fffffff; fEzL[0] = 0x7fffffff; }
    }

    const bool jin = (gj >= 0) && (gj < NYg);
    const float pyv = jin ? px_g[gj] : 0.f;

    float Ez[8], Hx[8], Hy[8], rc[8], dmp[8];
    #pragma unroll
    for (int r = 0; r < 8; ++r) {
        const int gi = gib + r;
        const bool in = jin && (gi >= 0) && (gi < NXg);
        if (in) {
            const size_t go = bb + (size_t)gi * NYg + gj;
            Ez[r] = Ez_g[go]; Hx[r] = Hx_g[go]; Hy[r] = Hy_g[go];
            rc[r] = rc_g[(size_t)gi * NYg + gj];
            dmp[r] = px_g[gi] * pyv;
        } else {
            Ez[r] = 0.f; Hx[r] = 0.f; Hy[r] = 0.f; rc[r] = 0.5f; dmp[r] = 0.f;
        }
    }
    float dmpA = 0.f;   // damp of the row just above this wave's rows
    { const int giA = gib - 1; if (jin && giA >= 0 && giA < NXg) dmpA = px_g[giA] * pyv; }

    const int djp = gj - 70;
    const int pport = (djp >= 0 && djp < 260 && (djp % 80) < 20) ? (djp / 80) : -1;
    const float phv = (pport >= 0) ? phase[b * 4 + pport] : 0.f;
    const bool gYlt = (gj < NYg - 1);
    const bool gYgt = (gj > 0);
    const bool hasSrc = (gib <= SRC_I) && (SRC_I < gib + 8);

    __syncthreads();   // ghosts + flag init visible; the ONLY barrier this round

    // ---- publish step-0 boundary data, release flags ----
    xEz0[0][(w << 6) + lj] = Ez[0];
    xEzL[0][((w + 1) << 6) + lj] = Ez[7];
    xHyL[0][((w + 1) << 6) + lj] = Hy[7];
    if (lj == 0) {
        __hip_atomic_store(&fEz0[w],     0, __ATOMIC_RELEASE, __HIP_MEMORY_SCOPE_WORKGROUP);
        __hip_atomic_store(&fEzL[w + 1], 0, __ATOMIC_RELEASE, __HIP_MEMORY_SCOPE_WORKGROUP);
    }

    for (int s = 0; s < RSTEPS; ++s) {
        const int p = s & 1;
        // acquire-spin: neighbors' step-s data ready (usually already satisfied)
        while (__hip_atomic_load(&fEz0[w + 1], __ATOMIC_ACQUIRE, __HIP_MEMORY_SCOPE_WORKGROUP) < s) {}
        const float ezB  = xEz0[p][((w + 1) << 6) + lj];   // Ez of row below (wave w+1 row0)
        while (__hip_atomic_load(&fEzL[w], __ATOMIC_ACQUIRE, __HIP_MEMORY_SCOPE_WORKGROUP) < s) {}
        const float ezAL = xEzL[p][(w << 6) + lj];         // Ez of row above (wave w-1 row7)
        const float hyAL = xHyL[p][(w << 6) + lj];         // Hy of row above (pre-update)
        // redundant Hy update of the row above — bitwise-identical inputs/expression
        const float dexA = (gib - 1 < NXg - 1) ? (Ez[0] - ezAL) : 0.f;
        const float hyA  = hupd(dmpA, hyAL, dexA);

        // ---- H update (registers + shuffles) ----
        float ezn[8];
        #pragma unroll
        for (int r = 0; r < 7; ++r) ezn[r] = Ez[r + 1];
        ezn[7] = ezB;
        #pragma unroll
        for (int r = 0; r < 8; ++r) {
            const int gi = gib + r;
            const float ezr = __shfl_down(Ez[r], 1, 64);
            const float dey = gYlt ? (ezr - Ez[r]) : 0.f;
            const float dex = (gi < NXg - 1) ? (ezn[r] - Ez[r]) : 0.f;
            Hx[r] = hupd(dmp[r], Hx[r], -dey);
            Hy[r] = hupd(dmp[r], Hy[r], dex);
        }

        // ---- E update + soft source ----
        const float tf = (float)(t0 + s);
        float hyprev = hyA;
        #pragma unroll
        for (int r = 0; r < 8; ++r) {
            const int gi = gib + r;
            const float hxl = __shfl_up(Hx[r], 1, 64);
            const float dhyx = (gi > 0) ? (Hy[r] - hyprev) : 0.f;
            const float dhxy = gYgt ? (Hx[r] - hxl) : 0.f;
            float ez = dmp[r] * (Ez[r] + rc[r] * (dhyx - dhxy));
            if (hasSrc && (gi == SRC_I) && (pport >= 0)) {
                const float a = tf * DT_F;                  // JAX f32 op order
                ez += sinf(TWOPI_F * a / PERIOD_F + PI_F * phv);
            }
            Ez[r] = ez;
            hyprev = Hy[r];
        }

        // ---- publish step s+1 boundary data (slot (s+1)&1), release flags ----
        if (s < RSTEPS - 1) {
            const int q = (s + 1) & 1;
            xEz0[q][(w << 6) + lj] = Ez[0];
            xEzL[q][((w + 1) << 6) + lj] = Ez[7];
            xHyL[q][((w + 1) << 6) + lj] = Hy[7];
            if (lj == 0) {
                __hip_atomic_store(&fEz0[w],     s + 1, __ATOMIC_RELEASE, __HIP_MEMORY_SCOPE_WORKGROUP);
                __hip_atomic_store(&fEzL[w + 1], s + 1, __ATOMIC_RELEASE, __HIP_MEMORY_SCOPE_WORKGROUP);
            }
        }
    }

    // store interior [HALO, HALO+TILE_B) — exact tiling
    if (lj >= HALO && lj < HALO + TILE_B) {
        #pragma unroll
        for (int r = 0; r < 8; ++r) {
            const int li = (w << 3) + r;
            if (li >= HALO && li < HALO + TILE_B) {
                const int gi = gx0 + li;
                const size_t go = bb + (size_t)gi * NYg + gj;
                Ez_g[go] = Ez[r];
                Hx_g[go] = Hx[r];
                Hy_g[go] = Hy[r];
            }
        }
    }
}

// ---- detector gather: out[b][p][k] = Ez[DET_I, 80*(p+1)-10+k] ----
__global__ void fdtd_gather(const float* __restrict__ Ez_g, float* __restrict__ out)
{
    int idx = threadIdx.x;
    if (idx < NB * 80) {
        int b = idx / 80, rem = idx % 80, p = rem / 20, k = rem % 20;
        int gj = (p + 1) * 80 - 10 + k;
        out[idx] = Ez_g[(size_t)b * NN + (size_t)DET_I * NYg + gj];
    }
}

extern "C" void kernel_launch(void* const* d_in, const int* in_sizes, int n_in,
                              void* d_out, int out_size, void* d_ws, size_t ws_size,
                              hipStream_t stream)
{
    const float* phase  = (const float*)d_in[0];   // (2,4) f32
    const float* radius = (const float*)d_in[1];   // (8,8) f32
    float* ws = (float*)d_ws;
    // workspace layout (floats): Ez[2*NN] | Hx[2*NN] | Hy[2*NN] | rc[NN] | px[400]
    float* Ez_g = ws;
    float* Hx_g = ws + 2 * NN;
    float* Hy_g = ws + 4 * NN;
    float* rc_g = ws + 6 * NN;
    float* px_g = ws + 7 * NN;

    fdtd_setup<<<(NN + 255) / 256, 256, 0, stream>>>(radius, Ez_g, Hx_g, Hy_g, rc_g, px_g);

    dim3 grid(NTI, NTI, NB);
    for (int r = 0; r < ROUNDS; ++r) {
        fdtd_round<<<grid, 512, 0, stream>>>(phase, Ez_g, Hx_g, Hy_g, rc_g, px_g, r * RSTEPS);
    }

    fdtd_gather<<<1, 256, 0, stream>>>(Ez_g, (float*)d_out);
}